// Round 6
// baseline (573.585 us; speedup 1.0000x reference)
//
#include <hip/hip_runtime.h>
#include <hip/hip_bf16.h>
#include <stdint.h>

#define H_   12
#define KV_  2
#define D_   128
#define HID_ 1536
#define B_   4
#define S_   2048
#define T_   (B_*S_)

typedef __attribute__((ext_vector_type(8))) short  bf16x8;
typedef __attribute__((ext_vector_type(4))) float  f32x4;

__device__ __forceinline__ ushort f2bf(float f) {
  union { float f; uint32_t u; } v; v.f = f;
  uint32_t u = v.u;
  return (ushort)((u + 0x7fffu + ((u >> 16) & 1u)) >> 16);  // RNE
}
__device__ __forceinline__ float bf2f(ushort u) {
  union { uint32_t u; float f; } v; v.u = ((uint32_t)u) << 16;
  return v.f;
}
__device__ __forceinline__ uint32_t cvtpk_bf16(float lo, float hi) {
  uint32_t r;
  asm("v_cvt_pk_bf16_f32 %0, %1, %2" : "=v"(r) : "v"(lo), "v"(hi));
  return r;
}

__device__ __forceinline__ void gload_lds16(const void* g, void* l) {
  __builtin_amdgcn_global_load_lds(
      (const __attribute__((address_space(1))) uint32_t*)g,
      (__attribute__((address_space(3))) uint32_t*)l, 16, 0, 0);
}

// ---------------- elementwise fp32 -> bf16 ----------------
__global__ __launch_bounds__(256) void cvt_f32_bf16(const float* __restrict__ in,
                                                    ushort* __restrict__ out, int n) {
  int i = (blockIdx.x * 256 + threadIdx.x) * 4;
  if (i + 3 < n) {
    float4 v = *(const float4*)&in[i];
    ushort4 o;
    o.x = f2bf(v.x); o.y = f2bf(v.y); o.z = f2bf(v.z); o.w = f2bf(v.w);
    *(ushort4*)&out[i] = o;
  }
}

// ---------------- transpose + convert: W (K,N) fp32 -> Wt (N,K) bf16 ----------------
__global__ __launch_bounds__(256) void transpose_cvt(const float* __restrict__ W,
                                                     ushort* __restrict__ Wt,
                                                     int K, int N) {
  __shared__ float tile[32][33];
  int k0 = blockIdx.x * 32, n0 = blockIdx.y * 32;
  int tx = threadIdx.x & 31, ty = threadIdx.x >> 5;  // ty 0..7
#pragma unroll
  for (int i = 0; i < 32; i += 8)
    tile[ty + i][tx] = W[(long)(k0 + ty + i) * N + n0 + tx];
  __syncthreads();
#pragma unroll
  for (int i = 0; i < 32; i += 8)
    Wt[(long)(n0 + ty + i) * K + k0 + tx] = f2bf(tile[tx][ty + i]);
}

// ---------------- GEMM: C(M,N) = A(M,K) * Bt(N,K)^T, bf16 in, bf16/f32 out ----------------
template <int OUT_F32>
__global__ __launch_bounds__(256, 2) void gemm_bt(const ushort* __restrict__ A,
                                                  const ushort* __restrict__ Bt,
                                                  void* __restrict__ Cv,
                                                  int M, int N, int K) {
  __shared__ ushort lA[128 * 32];
  __shared__ ushort lB[128 * 32];
  const int tid = threadIdx.x;
  const int lane = tid & 63, w = tid >> 6;
  const int wr = w >> 1, wc = w & 1;
  const int l15 = lane & 15, lh = lane >> 4;
  const long m0 = (long)blockIdx.x * 128, n0 = (long)blockIdx.y * 128;
  const ushort* Ab = A + m0 * K;
  const ushort* Bb = Bt + n0 * K;
  const int sr = tid >> 2;
  const int sc = (tid & 3) * 8;
  const int ldsoff = w * 512;
  f32x4 acc[4][4] = {};

  for (int k0 = 0; k0 < K; k0 += 32) {
#pragma unroll
    for (int it = 0; it < 2; ++it) {
      gload_lds16(Ab + (long)(it * 64 + sr) * K + k0 + sc, &lA[it * 2048 + ldsoff]);
      gload_lds16(Bb + (long)(it * 64 + sr) * K + k0 + sc, &lB[it * 2048 + ldsoff]);
    }
    __syncthreads();
    bf16x8 af[4], bfr[4];
    const int ra = (wr * 64 + l15) * 32 + lh * 8;
    const int rb = (wc * 64 + l15) * 32 + lh * 8;
#pragma unroll
    for (int i = 0; i < 4; ++i) {
      af[i]  = *(const bf16x8*)&lA[ra + i * 16 * 32];
      bfr[i] = *(const bf16x8*)&lB[rb + i * 16 * 32];
    }
#pragma unroll
    for (int i = 0; i < 4; ++i)
#pragma unroll
      for (int j = 0; j < 4; ++j)
        acc[i][j] = __builtin_amdgcn_mfma_f32_16x16x32_bf16(af[i], bfr[j], acc[i][j], 0, 0, 0);
    __syncthreads();
  }
#pragma unroll
  for (int i = 0; i < 4; ++i) {
#pragma unroll
    for (int q = 0; q < 4; ++q) {
      long row = m0 + wr * 64 + i * 16 + lh * 4 + q;
#pragma unroll
      for (int j = 0; j < 4; ++j) {
        long col = n0 + wc * 64 + j * 16 + l15;
        float v = acc[i][j][q];
        if (OUT_F32) ((float*)Cv)[row * N + col] = v;
        else         ((ushort*)Cv)[row * N + col] = f2bf(v);
      }
    }
  }
}

// ---------------- fused RMSNorm + RoPE (+ optional scale), wave per (token, head) ----------------
template <int NH>
__global__ __launch_bounds__(256) void normrope(const ushort* __restrict__ X,  // [T][xstride]
                                                int xstride,
                                                const float* __restrict__ w,   // [128]
                                                const float* __restrict__ cosb,// [T][64]
                                                const float* __restrict__ sinb,
                                                ushort* __restrict__ Y,        // [B][NH][S][128]
                                                float scale) {
  int wid = (int)((blockIdx.x * 256 + threadIdx.x) >> 6);
  int lane = threadIdx.x & 63;
  if (wid >= T_ * NH) return;
  int t = wid / NH, h = wid % NH;
  const ushort* xr = X + (long)t * xstride + h * 128;
  float x1 = bf2f(xr[lane]);
  float x2 = bf2f(xr[lane + 64]);
  float ss = x1 * x1 + x2 * x2;
#pragma unroll
  for (int off = 32; off; off >>= 1) ss += __shfl_xor(ss, off);
  float r = rsqrtf(ss * (1.0f / 128.0f) + 1e-6f);
  float y1 = x1 * r * w[lane] * scale;
  float y2 = x2 * r * w[lane + 64] * scale;
  float c = cosb[(long)t * 64 + lane], s = sinb[(long)t * 64 + lane];
  float o1 = y1 * c - y2 * s;
  float o2 = y1 * s + y2 * c;
  int b = t / S_, sq = t % S_;
  ushort* yr = Y + ((long)(b * NH + h) * S_ + sq) * 128;
  yr[lane]      = f2bf(o1);
  yr[lane + 64] = f2bf(o2);
}

// ---------------- V transpose: [T][vstride] (col voff+) -> [B][KV][128][S] ----------------
__global__ __launch_bounds__(256) void vtrans(const ushort* __restrict__ V, int vstride, int voff,
                                              ushort* __restrict__ Vt) {
  __shared__ ushort tile[32][33];
  int s0 = blockIdx.x * 32, d0 = blockIdx.y * 32;
  int bk = blockIdx.z;
  int b = bk / KV_, g = bk % KV_;
  int tx = threadIdx.x & 31, ty = threadIdx.x >> 5;
#pragma unroll
  for (int i = 0; i < 32; i += 8)
    tile[ty + i][tx] = V[(long)(b * S_ + s0 + ty + i) * vstride + voff + g * 128 + d0 + tx];
  __syncthreads();
#pragma unroll
  for (int i = 0; i < 32; i += 8)
    Vt[(long)(bk * 128 + d0 + ty + i) * S_ + s0 + tx] = tile[tx][ty + i];
}

// ---------------- flash attention, causal, GQA ----------------
// Round-3 structure (LDS-staged K/V, reg prefetch, swapped QK^T, in-reg softmax, T13) with:
//  - LDS 40960B (lP halved to 2KB/wave, consumed per kf2-half)  -> 4 blocks/CU capacity
//  - launch_bounds(256,4): VGPR<=128 (r3 footprint 124, no spill) -> 16 waves/CU
//  - 768 blocks = exactly 3 resident/CU, single residency round
//  - lK full-bijection XOR swizzle (l15<<4): conflict-free K-frag reads
//  - serpentine qt order: each CU's 3 blocks mix heavy/light
__global__ __launch_bounds__(256, 4) void attn(const ushort* __restrict__ Qa, // [B][H][S][D]
                                               const ushort* __restrict__ Ka, // [B][KV][S][D]
                                               const ushort* __restrict__ Vt, // [B][KV][D][S]
                                               ushort* __restrict__ Oa) {     // [T][H*D]
  __shared__ ushort lK[64 * 128];   // [k][d], xor-swizzled (full 16-slot bijection)
  __shared__ ushort lV[128 * 64];   // [d][k], xor-swizzled
  __shared__ ushort lP[4 * 32 * 32];// per-wave [q][32k half], xor-swizzled
  const int tid = threadIdx.x, lane = tid & 63, w = tid >> 6;
  const int l15 = lane & 15, lh = lane >> 4;
  char* cK = (char*)lK;
  char* cV = (char*)lV;
  char* cP = (char*)lP + w * 2048;
  const int swzK = l15 << 4;          // lK rows: 256B, 16 slots, full bijection
  const int swzV = (l15 & 7) << 4;    // lV rows: 128B, 8 slots
  const int swzP = (l15 & 3) << 4;    // lP rows:  64B, 4 slots

  // serpentine LPT-ish: qt sequence 15,0,14,1,... mixes heavy/light across CUs
  const int qi = blockIdx.x / 48;
  const int qt = (qi & 1) ? (qi >> 1) : (15 - (qi >> 1));
  const int bh = blockIdx.x % 48;
  const int b = bh / H_, h = bh % H_, g = h / (H_ / KV_);
  const int q0 = qt * 128;
  const ushort* Kb = Ka + (long)(b * KV_ + g) * S_ * 128;
  const ushort* Vb = Vt + (long)(b * KV_ + g) * 128 * S_;
  const ushort* Qb = Qa + ((long)(b * H_ + h) * S_ + q0 + w * 32) * 128;

  bf16x8 qf[2][4];
#pragma unroll
  for (int m = 0; m < 2; ++m)
#pragma unroll
    for (int kd = 0; kd < 4; ++kd)
      qf[m][kd] = *(const bf16x8*)&Qb[(m * 16 + l15) * 128 + kd * 32 + lh * 8];

  f32x4 o[2][8] = {};
  float mr[2] = {-INFINITY, -INFINITY};
  float lr[2] = {0.f, 0.f};
  const int nt = 2 * qt + 2;

  bf16x8 kreg[4], vreg[4];
#define LDTILE(K0) do { \
  _Pragma("unroll") for (int it = 0; it < 4; ++it) \
    kreg[it] = *(const bf16x8*)&Kb[(long)((K0) + it * 16 + (tid >> 4)) * 128 + (tid & 15) * 8]; \
  _Pragma("unroll") for (int it = 0; it < 4; ++it) \
    vreg[it] = *(const bf16x8*)&Vb[(long)(it * 32 + (tid >> 3)) * S_ + (K0) + (tid & 7) * 8]; \
} while (0)

  LDTILE(0);
  for (int t = 0; t < nt; ++t) {
    const int k0 = t * 64;
    __syncthreads();   // previous tile's consumers done
#pragma unroll
    for (int it = 0; it < 4; ++it) {
      int r = it * 16 + (tid >> 4);   // r&15 == tid>>4
      *(bf16x8*)(cK + r * 256 + (((tid & 15) * 16) ^ (((tid >> 4) & 15) << 4))) = kreg[it];
    }
#pragma unroll
    for (int it = 0; it < 4; ++it) {
      int r = it * 32 + (tid >> 3);
      *(bf16x8*)(cV + r * 128 + (((tid & 7) * 16) ^ ((r & 7) << 4))) = vreg[it];
    }
    __syncthreads();   // stage visible
    if (t + 1 < nt) LDTILE(k0 + 64);   // in flight during compute

    if (k0 <= q0 + w * 32 + 31) {
      // ---- QK^T, swapped operands: sfr[m][n] = S[k-row][q-col=l15] ----
      f32x4 sfr[2][4] = {};
#pragma unroll
      for (int kd = 0; kd < 4; ++kd) {
        bf16x8 kf[4];
#pragma unroll
        for (int n = 0; n < 4; ++n)
          kf[n] = *(const bf16x8*)(cK + (n * 16 + l15) * 256 + ((kd * 64 + lh * 16) ^ swzK));
#pragma unroll
        for (int m = 0; m < 2; ++m)
#pragma unroll
          for (int n = 0; n < 4; ++n)
            sfr[m][n] = __builtin_amdgcn_mfma_f32_16x16x32_bf16(kf[n], qf[m][kd], sfr[m][n], 0, 0, 0);
      }
      const bool boundary = (k0 + 63 > q0 + w * 32);
      float pm[2];
#pragma unroll
      for (int m = 0; m < 2; ++m) {
        const int rowm = q0 + w * 32 + m * 16 + l15;
        if (boundary) {
#pragma unroll
          for (int n = 0; n < 4; ++n) {
            int kb = k0 + n * 16 + lh * 4;
#pragma unroll
            for (int qr = 0; qr < 4; ++qr)
              if (kb + qr > rowm) sfr[m][n][qr] = -INFINITY;
          }
        }
        float x = fmaxf(fmaxf(sfr[m][0][0], sfr[m][0][1]), fmaxf(sfr[m][0][2], sfr[m][0][3]));
#pragma unroll
        for (int n = 1; n < 4; ++n)
          x = fmaxf(x, fmaxf(fmaxf(sfr[m][n][0], sfr[m][n][1]), fmaxf(sfr[m][n][2], sfr[m][n][3])));
        x = fmaxf(x, __shfl_xor(x, 16));
        x = fmaxf(x, __shfl_xor(x, 32));
        pm[m] = x;
      }
      // T13 defer-max
      int ok = (pm[0] <= mr[0] + 8.f) && (pm[1] <= mr[1] + 8.f);
      if (!__all(ok)) {
        float corr[2];
#pragma unroll
        for (int m = 0; m < 2; ++m) {
          float mn = fmaxf(mr[m], pm[m]);
          corr[m] = exp2f(mr[m] - mn);
          mr[m] = mn;
          lr[m] *= corr[m];
        }
#pragma unroll
        for (int m = 0; m < 2; ++m) {
          float cf[4];
#pragma unroll
          for (int qr = 0; qr < 4; ++qr) cf[qr] = __shfl(corr[m], lh * 4 + qr);
#pragma unroll
          for (int d = 0; d < 8; ++d)
#pragma unroll
            for (int qr = 0; qr < 4; ++qr) o[m][d][qr] *= cf[qr];
        }
      }
      // ---- P = exp2(S - m) in regs (sfr), row-sum ----
#pragma unroll
      for (int m = 0; m < 2; ++m) {
        float rs = 0.f;
#pragma unroll
        for (int n = 0; n < 4; ++n) {
          float p0 = exp2f(sfr[m][n][0] - mr[m]);
          float p1 = exp2f(sfr[m][n][1] - mr[m]);
          float p2 = exp2f(sfr[m][n][2] - mr[m]);
          float p3 = exp2f(sfr[m][n][3] - mr[m]);
          sfr[m][n][0] = p0; sfr[m][n][1] = p1; sfr[m][n][2] = p2; sfr[m][n][3] = p3;
          rs += (p0 + p1) + (p2 + p3);
        }
        rs += __shfl_xor(rs, 16);
        rs += __shfl_xor(rs, 32);
        lr[m] += rs;
      }
      // ---- PV per 32-wide half: pack P half -> per-wave lP (2KB), read pf, MFMA ----
#pragma unroll
      for (int kf2 = 0; kf2 < 2; ++kf2) {
#pragma unroll
        for (int m = 0; m < 2; ++m)
#pragma unroll
          for (int nl = 0; nl < 2; ++nl) {
            const int n = kf2 * 2 + nl;
            uint2 pk;
            pk.x = cvtpk_bf16(sfr[m][n][0], sfr[m][n][1]);
            pk.y = cvtpk_bf16(sfr[m][n][2], sfr[m][n][3]);
            *(uint2*)(cP + (m * 16 + l15) * 64 + ((nl * 32 + lh * 8) ^ swzP)) = pk;
          }
        const int cb = (lh * 16) ^ swzP;
        bf16x8 pf0 = *(const bf16x8*)(cP + l15 * 64 + cb);
        bf16x8 pf1 = *(const bf16x8*)(cP + (16 + l15) * 64 + cb);
        const int cv = (kf2 * 64 + lh * 16);
#pragma unroll
        for (int dblk = 0; dblk < 8; ++dblk) {
          bf16x8 vf = *(const bf16x8*)(cV + (dblk * 16 + l15) * 128 + (cv ^ swzV));
          o[0][dblk] = __builtin_amdgcn_mfma_f32_16x16x32_bf16(pf0, vf, o[0][dblk], 0, 0, 0);
          o[1][dblk] = __builtin_amdgcn_mfma_f32_16x16x32_bf16(pf1, vf, o[1][dblk], 0, 0, 0);
        }
      }
    }
  }
#undef LDTILE
  // ---- epilogue ----
#pragma unroll
  for (int m = 0; m < 2; ++m) {
    float inv = 1.f / lr[m];
#pragma unroll
    for (int qr = 0; qr < 4; ++qr) {
      float iv = __shfl(inv, lh * 4 + qr);
      long trow = (long)b * S_ + q0 + w * 32 + m * 16 + lh * 4 + qr;
#pragma unroll
      for (int dblk = 0; dblk < 8; ++dblk)
        Oa[trow * 1536 + h * 128 + dblk * 16 + l15] = f2bf(o[m][dblk][qr] * iv);
    }
  }
}

extern "C" void kernel_launch(void* const* d_in, const int* in_sizes, int n_in,
                              void* d_out, int out_size, void* d_ws, size_t ws_size,
                              hipStream_t stream) {
  const float* hs   = (const float*)d_in[0];
  const float* cosb = (const float*)d_in[1];
  const float* sinb = (const float*)d_in[2];
  const float* Wq   = (const float*)d_in[3];
  const float* Wk   = (const float*)d_in[4];
  const float* Wv   = (const float*)d_in[5];
  const float* Wo   = (const float*)d_in[6];
  const float* qw   = (const float*)d_in[7];
  const float* kw   = (const float*)d_in[8];
  (void)in_sizes; (void)n_in; (void)out_size; (void)ws_size;

  char* ws = (char*)d_ws;
  size_t off = 0;
  auto alloc = [&](size_t bytes) {
    void* p = ws + off;
    off += (bytes + 255) & ~(size_t)255;
    return p;
  };
  ushort* Xb  = (ushort*)alloc((size_t)T_ * HID_ * 2);
  ushort* Wqt = (ushort*)alloc((size_t)HID_ * HID_ * 2);
  ushort* Wkt = (ushort*)alloc((size_t)256 * HID_ * 2);  // contiguous with Wvt
  ushort* Wvt = (ushort*)alloc((size_t)256 * HID_ * 2);
  ushort* Wot = (ushort*)alloc((size_t)HID_ * HID_ * 2);
  ushort* qb  = (ushort*)alloc((size_t)T_ * 1536 * 2);
  ushort* kvb = (ushort*)alloc((size_t)T_ * 512 * 2);
  ushort* ka  = (ushort*)alloc((size_t)T_ * 256 * 2);
  ushort* vt  = (ushort*)alloc((size_t)T_ * 256 * 2);
  ushort* qa = Xb;  // q attn layout overwrites Xb after last GEMM
  ushort* ao = qb;  // attn out overwrites q-proj after normrope-q consumed it

  const float SCL = 0.08838834764831845f * 1.44269504088896f;  // D^-0.5 * log2(e)

  cvt_f32_bf16<<<(T_ * HID_ / 4 + 255) / 256, 256, 0, stream>>>(hs, Xb, T_ * HID_);
  transpose_cvt<<<dim3(HID_ / 32, HID_ / 32), 256, 0, stream>>>(Wq, Wqt, HID_, HID_);
  transpose_cvt<<<dim3(HID_ / 32, 256 / 32), 256, 0, stream>>>(Wk, Wkt, HID_, 256);
  transpose_cvt<<<dim3(HID_ / 32, 256 / 32), 256, 0, stream>>>(Wv, Wvt, HID_, 256);
  transpose_cvt<<<dim3(HID_ / 32, HID_ / 32), 256, 0, stream>>>(Wo, Wot, HID_, HID_);

  gemm_bt<0><<<dim3(T_ / 128, 1536 / 128), 256, 0, stream>>>(Xb, Wqt, qb, T_, 1536, HID_);
  gemm_bt<0><<<dim3(T_ / 128, 512 / 128), 256, 0, stream>>>(Xb, Wkt, kvb, T_, 512, HID_);

  normrope<H_><<<(T_ * H_ + 3) / 4, 256, 0, stream>>>(qb, 1536, qw, cosb, sinb, qa, SCL);
  normrope<KV_><<<(T_ * KV_ + 3) / 4, 256, 0, stream>>>(kvb, 512, kw, cosb, sinb, ka, 1.0f);
  vtrans<<<dim3(S_ / 32, 128 / 32, B_ * KV_), 256, 0, stream>>>(kvb, 512, 256, vt);

  attn<<<768, 256, 0, stream>>>(qa, ka, vt, ao);

  gemm_bt<1><<<dim3(T_ / 128, 1536 / 128), 256, 0, stream>>>(ao, Wot, (float*)d_out, T_, 1536, HID_);
}

// Round 7
// 291.647 us; speedup vs baseline: 1.9667x; 1.9667x over previous
//
#include <hip/hip_runtime.h>
#include <hip/hip_bf16.h>
#include <stdint.h>

#define H_   12
#define KV_  2
#define D_   128
#define HID_ 1536
#define B_   4
#define S_   2048
#define T_   (B_*S_)

typedef __attribute__((ext_vector_type(8))) short  bf16x8;
typedef __attribute__((ext_vector_type(4))) float  f32x4;

__device__ __forceinline__ ushort f2bf(float f) {
  union { float f; uint32_t u; } v; v.f = f;
  uint32_t u = v.u;
  return (ushort)((u + 0x7fffu + ((u >> 16) & 1u)) >> 16);  // RNE
}
__device__ __forceinline__ float bf2f(ushort u) {
  union { uint32_t u; float f; } v; v.u = ((uint32_t)u) << 16;
  return v.f;
}
__device__ __forceinline__ uint32_t cvtpk_bf16(float lo, float hi) {
  uint32_t r;
  asm("v_cvt_pk_bf16_f32 %0, %1, %2" : "=v"(r) : "v"(lo), "v"(hi));
  return r;
}

__device__ __forceinline__ void gload_lds16(const void* g, void* l) {
  __builtin_amdgcn_global_load_lds(
      (const __attribute__((address_space(1))) uint32_t*)g,
      (__attribute__((address_space(3))) uint32_t*)l, 16, 0, 0);
}

// ---------------- elementwise fp32 -> bf16 ----------------
__global__ __launch_bounds__(256) void cvt_f32_bf16(const float* __restrict__ in,
                                                    ushort* __restrict__ out, int n) {
  int i = (blockIdx.x * 256 + threadIdx.x) * 4;
  if (i + 3 < n) {
    float4 v = *(const float4*)&in[i];
    ushort4 o;
    o.x = f2bf(v.x); o.y = f2bf(v.y); o.z = f2bf(v.z); o.w = f2bf(v.w);
    *(ushort4*)&out[i] = o;
  }
}

// ---------------- transpose + convert: W (K,N) fp32 -> Wt (N,K) bf16 ----------------
__global__ __launch_bounds__(256) void transpose_cvt(const float* __restrict__ W,
                                                     ushort* __restrict__ Wt,
                                                     int K, int N) {
  __shared__ float tile[32][33];
  int k0 = blockIdx.x * 32, n0 = blockIdx.y * 32;
  int tx = threadIdx.x & 31, ty = threadIdx.x >> 5;  // ty 0..7
#pragma unroll
  for (int i = 0; i < 32; i += 8)
    tile[ty + i][tx] = W[(long)(k0 + ty + i) * N + n0 + tx];
  __syncthreads();
#pragma unroll
  for (int i = 0; i < 32; i += 8)
    Wt[(long)(n0 + ty + i) * K + k0 + tx] = f2bf(tile[tx][ty + i]);
}

// ---------------- GEMM: C(M,N) = A(M,K) * Bt(N,K)^T, bf16 in, bf16/f32 out ----------------
template <int OUT_F32>
__global__ __launch_bounds__(256, 2) void gemm_bt(const ushort* __restrict__ A,
                                                  const ushort* __restrict__ Bt,
                                                  void* __restrict__ Cv,
                                                  int M, int N, int K) {
  __shared__ ushort lA[128 * 32];
  __shared__ ushort lB[128 * 32];
  const int tid = threadIdx.x;
  const int lane = tid & 63, w = tid >> 6;
  const int wr = w >> 1, wc = w & 1;
  const int l15 = lane & 15, lh = lane >> 4;
  const long m0 = (long)blockIdx.x * 128, n0 = (long)blockIdx.y * 128;
  const ushort* Ab = A + m0 * K;
  const ushort* Bb = Bt + n0 * K;
  const int sr = tid >> 2;
  const int sc = (tid & 3) * 8;
  const int ldsoff = w * 512;
  f32x4 acc[4][4] = {};

  for (int k0 = 0; k0 < K; k0 += 32) {
#pragma unroll
    for (int it = 0; it < 2; ++it) {
      gload_lds16(Ab + (long)(it * 64 + sr) * K + k0 + sc, &lA[it * 2048 + ldsoff]);
      gload_lds16(Bb + (long)(it * 64 + sr) * K + k0 + sc, &lB[it * 2048 + ldsoff]);
    }
    __syncthreads();
    bf16x8 af[4], bfr[4];
    const int ra = (wr * 64 + l15) * 32 + lh * 8;
    const int rb = (wc * 64 + l15) * 32 + lh * 8;
#pragma unroll
    for (int i = 0; i < 4; ++i) {
      af[i]  = *(const bf16x8*)&lA[ra + i * 16 * 32];
      bfr[i] = *(const bf16x8*)&lB[rb + i * 16 * 32];
    }
#pragma unroll
    for (int i = 0; i < 4; ++i)
#pragma unroll
      for (int j = 0; j < 4; ++j)
        acc[i][j] = __builtin_amdgcn_mfma_f32_16x16x32_bf16(af[i], bfr[j], acc[i][j], 0, 0, 0);
    __syncthreads();
  }
#pragma unroll
  for (int i = 0; i < 4; ++i) {
#pragma unroll
    for (int q = 0; q < 4; ++q) {
      long row = m0 + wr * 64 + i * 16 + lh * 4 + q;
#pragma unroll
      for (int j = 0; j < 4; ++j) {
        long col = n0 + wc * 64 + j * 16 + l15;
        float v = acc[i][j][q];
        if (OUT_F32) ((float*)Cv)[row * N + col] = v;
        else         ((ushort*)Cv)[row * N + col] = f2bf(v);
      }
    }
  }
}

// ---------------- fused RMSNorm + RoPE (+ optional scale), wave per (token, head) ----------------
template <int NH>
__global__ __launch_bounds__(256) void normrope(const ushort* __restrict__ X,  // [T][xstride]
                                                int xstride,
                                                const float* __restrict__ w,   // [128]
                                                const float* __restrict__ cosb,// [T][64]
                                                const float* __restrict__ sinb,
                                                ushort* __restrict__ Y,        // [B][NH][S][128]
                                                float scale) {
  int wid = (int)((blockIdx.x * 256 + threadIdx.x) >> 6);
  int lane = threadIdx.x & 63;
  if (wid >= T_ * NH) return;
  int t = wid / NH, h = wid % NH;
  const ushort* xr = X + (long)t * xstride + h * 128;
  float x1 = bf2f(xr[lane]);
  float x2 = bf2f(xr[lane + 64]);
  float ss = x1 * x1 + x2 * x2;
#pragma unroll
  for (int off = 32; off; off >>= 1) ss += __shfl_xor(ss, off);
  float r = rsqrtf(ss * (1.0f / 128.0f) + 1e-6f);
  float y1 = x1 * r * w[lane] * scale;
  float y2 = x2 * r * w[lane + 64] * scale;
  float c = cosb[(long)t * 64 + lane], s = sinb[(long)t * 64 + lane];
  float o1 = y1 * c - y2 * s;
  float o2 = y1 * s + y2 * c;
  int b = t / S_, sq = t % S_;
  ushort* yr = Y + ((long)(b * NH + h) * S_ + sq) * 128;
  yr[lane]      = f2bf(o1);
  yr[lane + 64] = f2bf(o2);
}

// ---------------- V transpose: [T][vstride] (col voff+) -> [B][KV][128][S] ----------------
__global__ __launch_bounds__(256) void vtrans(const ushort* __restrict__ V, int vstride, int voff,
                                              ushort* __restrict__ Vt) {
  __shared__ ushort tile[32][33];
  int s0 = blockIdx.x * 32, d0 = blockIdx.y * 32;
  int bk = blockIdx.z;
  int b = bk / KV_, g = bk % KV_;
  int tx = threadIdx.x & 31, ty = threadIdx.x >> 5;
#pragma unroll
  for (int i = 0; i < 32; i += 8)
    tile[ty + i][tx] = V[(long)(b * S_ + s0 + ty + i) * vstride + voff + g * 128 + d0 + tx];
  __syncthreads();
#pragma unroll
  for (int i = 0; i < 32; i += 8)
    Vt[(long)(bk * 128 + d0 + ty + i) * S_ + s0 + tx] = tile[tx][ty + i];
}

// ---------------- flash attention, causal, GQA ----------------
// Round-3 structure (LDS-staged K/V, reg prefetch, swapped QK^T, in-reg softmax, T13) with:
//  - launch_bounds(256,2): VGPR cap 256 -> compiler uses ~124, NO SPILL.
//    (Empirical: (256,n) caps VGPR at ~256/n; n=3/4 forced 84/64 VGPR -> massive scratch
//     spill, WRITE_SIZE 0.4-0.7 GB. HW occupancy steps at VGPR 64/128/256, so VGPR<=128
//     already allows 4 waves/SIMD without any launch_bounds coercion.)
//  - LDS 40960B (lP halved to 2KB/wave, consumed per kf2-half) -> 4 blocks/CU LDS limit
//  - 768 blocks = 3 resident/CU, single residency round
//  - lK full-bijection XOR swizzle (l15<<4); serpentine qt order mixes heavy/light
__global__ __launch_bounds__(256, 2) void attn(const ushort* __restrict__ Qa, // [B][H][S][D]
                                               const ushort* __restrict__ Ka, // [B][KV][S][D]
                                               const ushort* __restrict__ Vt, // [B][KV][D][S]
                                               ushort* __restrict__ Oa) {     // [T][H*D]
  __shared__ ushort lK[64 * 128];   // [k][d], xor-swizzled (full 16-slot bijection)
  __shared__ ushort lV[128 * 64];   // [d][k], xor-swizzled
  __shared__ ushort lP[4 * 32 * 32];// per-wave [q][32k half], xor-swizzled
  const int tid = threadIdx.x, lane = tid & 63, w = tid >> 6;
  const int l15 = lane & 15, lh = lane >> 4;
  char* cK = (char*)lK;
  char* cV = (char*)lV;
  char* cP = (char*)lP + w * 2048;
  const int swzK = l15 << 4;          // lK rows: 256B, 16 slots, full bijection
  const int swzV = (l15 & 7) << 4;    // lV rows: 128B, 8 slots
  const int swzP = (l15 & 3) << 4;    // lP rows:  64B, 4 slots

  // serpentine: qt sequence 15,0,14,1,... mixes heavy/light across CUs
  const int qi = blockIdx.x / 48;
  const int qt = (qi & 1) ? (qi >> 1) : (15 - (qi >> 1));
  const int bh = blockIdx.x % 48;
  const int b = bh / H_, h = bh % H_, g = h / (H_ / KV_);
  const int q0 = qt * 128;
  const ushort* Kb = Ka + (long)(b * KV_ + g) * S_ * 128;
  const ushort* Vb = Vt + (long)(b * KV_ + g) * 128 * S_;
  const ushort* Qb = Qa + ((long)(b * H_ + h) * S_ + q0 + w * 32) * 128;

  bf16x8 qf[2][4];
#pragma unroll
  for (int m = 0; m < 2; ++m)
#pragma unroll
    for (int kd = 0; kd < 4; ++kd)
      qf[m][kd] = *(const bf16x8*)&Qb[(m * 16 + l15) * 128 + kd * 32 + lh * 8];

  f32x4 o[2][8] = {};
  float mr[2] = {-INFINITY, -INFINITY};
  float lr[2] = {0.f, 0.f};
  const int nt = 2 * qt + 2;

  bf16x8 kreg[4], vreg[4];
#define LDTILE(K0) do { \
  _Pragma("unroll") for (int it = 0; it < 4; ++it) \
    kreg[it] = *(const bf16x8*)&Kb[(long)((K0) + it * 16 + (tid >> 4)) * 128 + (tid & 15) * 8]; \
  _Pragma("unroll") for (int it = 0; it < 4; ++it) \
    vreg[it] = *(const bf16x8*)&Vb[(long)(it * 32 + (tid >> 3)) * S_ + (K0) + (tid & 7) * 8]; \
} while (0)

  LDTILE(0);
  for (int t = 0; t < nt; ++t) {
    const int k0 = t * 64;
    __syncthreads();   // previous tile's consumers done
#pragma unroll
    for (int it = 0; it < 4; ++it) {
      int r = it * 16 + (tid >> 4);   // r&15 == tid>>4
      *(bf16x8*)(cK + r * 256 + (((tid & 15) * 16) ^ (((tid >> 4) & 15) << 4))) = kreg[it];
    }
#pragma unroll
    for (int it = 0; it < 4; ++it) {
      int r = it * 32 + (tid >> 3);
      *(bf16x8*)(cV + r * 128 + (((tid & 7) * 16) ^ ((r & 7) << 4))) = vreg[it];
    }
    __syncthreads();   // stage visible
    if (t + 1 < nt) LDTILE(k0 + 64);   // in flight during compute

    if (k0 <= q0 + w * 32 + 31) {
      // ---- QK^T, swapped operands: sfr[m][n] = S[k-row][q-col=l15] ----
      f32x4 sfr[2][4] = {};
#pragma unroll
      for (int kd = 0; kd < 4; ++kd) {
        bf16x8 kf[4];
#pragma unroll
        for (int n = 0; n < 4; ++n)
          kf[n] = *(const bf16x8*)(cK + (n * 16 + l15) * 256 + ((kd * 64 + lh * 16) ^ swzK));
#pragma unroll
        for (int m = 0; m < 2; ++m)
#pragma unroll
          for (int n = 0; n < 4; ++n)
            sfr[m][n] = __builtin_amdgcn_mfma_f32_16x16x32_bf16(kf[n], qf[m][kd], sfr[m][n], 0, 0, 0);
      }
      const bool boundary = (k0 + 63 > q0 + w * 32);
      float pm[2];
#pragma unroll
      for (int m = 0; m < 2; ++m) {
        const int rowm = q0 + w * 32 + m * 16 + l15;
        if (boundary) {
#pragma unroll
          for (int n = 0; n < 4; ++n) {
            int kb = k0 + n * 16 + lh * 4;
#pragma unroll
            for (int qr = 0; qr < 4; ++qr)
              if (kb + qr > rowm) sfr[m][n][qr] = -INFINITY;
          }
        }
        float x = fmaxf(fmaxf(sfr[m][0][0], sfr[m][0][1]), fmaxf(sfr[m][0][2], sfr[m][0][3]));
#pragma unroll
        for (int n = 1; n < 4; ++n)
          x = fmaxf(x, fmaxf(fmaxf(sfr[m][n][0], sfr[m][n][1]), fmaxf(sfr[m][n][2], sfr[m][n][3])));
        x = fmaxf(x, __shfl_xor(x, 16));
        x = fmaxf(x, __shfl_xor(x, 32));
        pm[m] = x;
      }
      // T13 defer-max
      int ok = (pm[0] <= mr[0] + 8.f) && (pm[1] <= mr[1] + 8.f);
      if (!__all(ok)) {
        float corr[2];
#pragma unroll
        for (int m = 0; m < 2; ++m) {
          float mn = fmaxf(mr[m], pm[m]);
          corr[m] = exp2f(mr[m] - mn);
          mr[m] = mn;
          lr[m] *= corr[m];
        }
#pragma unroll
        for (int m = 0; m < 2; ++m) {
          float cf[4];
#pragma unroll
          for (int qr = 0; qr < 4; ++qr) cf[qr] = __shfl(corr[m], lh * 4 + qr);
#pragma unroll
          for (int d = 0; d < 8; ++d)
#pragma unroll
            for (int qr = 0; qr < 4; ++qr) o[m][d][qr] *= cf[qr];
        }
      }
      // ---- P = exp2(S - m) in regs (sfr), row-sum ----
#pragma unroll
      for (int m = 0; m < 2; ++m) {
        float rs = 0.f;
#pragma unroll
        for (int n = 0; n < 4; ++n) {
          float p0 = exp2f(sfr[m][n][0] - mr[m]);
          float p1 = exp2f(sfr[m][n][1] - mr[m]);
          float p2 = exp2f(sfr[m][n][2] - mr[m]);
          float p3 = exp2f(sfr[m][n][3] - mr[m]);
          sfr[m][n][0] = p0; sfr[m][n][1] = p1; sfr[m][n][2] = p2; sfr[m][n][3] = p3;
          rs += (p0 + p1) + (p2 + p3);
        }
        rs += __shfl_xor(rs, 16);
        rs += __shfl_xor(rs, 32);
        lr[m] += rs;
      }
      // ---- PV per 32-wide half: pack P half -> per-wave lP (2KB), read pf, MFMA ----
#pragma unroll
      for (int kf2 = 0; kf2 < 2; ++kf2) {
#pragma unroll
        for (int m = 0; m < 2; ++m)
#pragma unroll
          for (int nl = 0; nl < 2; ++nl) {
            const int n = kf2 * 2 + nl;
            uint2 pk;
            pk.x = cvtpk_bf16(sfr[m][n][0], sfr[m][n][1]);
            pk.y = cvtpk_bf16(sfr[m][n][2], sfr[m][n][3]);
            *(uint2*)(cP + (m * 16 + l15) * 64 + ((nl * 32 + lh * 8) ^ swzP)) = pk;
          }
        const int cb = (lh * 16) ^ swzP;
        bf16x8 pf0 = *(const bf16x8*)(cP + l15 * 64 + cb);
        bf16x8 pf1 = *(const bf16x8*)(cP + (16 + l15) * 64 + cb);
        const int cv = (kf2 * 64 + lh * 16);
#pragma unroll
        for (int dblk = 0; dblk < 8; ++dblk) {
          bf16x8 vf = *(const bf16x8*)(cV + (dblk * 16 + l15) * 128 + (cv ^ swzV));
          o[0][dblk] = __builtin_amdgcn_mfma_f32_16x16x32_bf16(pf0, vf, o[0][dblk], 0, 0, 0);
          o[1][dblk] = __builtin_amdgcn_mfma_f32_16x16x32_bf16(pf1, vf, o[1][dblk], 0, 0, 0);
        }
      }
    }
  }
#undef LDTILE
  // ---- epilogue ----
#pragma unroll
  for (int m = 0; m < 2; ++m) {
    float inv = 1.f / lr[m];
#pragma unroll
    for (int qr = 0; qr < 4; ++qr) {
      float iv = __shfl(inv, lh * 4 + qr);
      long trow = (long)b * S_ + q0 + w * 32 + m * 16 + lh * 4 + qr;
#pragma unroll
      for (int dblk = 0; dblk < 8; ++dblk)
        Oa[trow * 1536 + h * 128 + dblk * 16 + l15] = f2bf(o[m][dblk][qr] * iv);
    }
  }
}

extern "C" void kernel_launch(void* const* d_in, const int* in_sizes, int n_in,
                              void* d_out, int out_size, void* d_ws, size_t ws_size,
                              hipStream_t stream) {
  const float* hs   = (const float*)d_in[0];
  const float* cosb = (const float*)d_in[1];
  const float* sinb = (const float*)d_in[2];
  const float* Wq   = (const float*)d_in[3];
  const float* Wk   = (const float*)d_in[4];
  const float* Wv   = (const float*)d_in[5];
  const float* Wo   = (const float*)d_in[6];
  const float* qw   = (const float*)d_in[7];
  const float* kw   = (const float*)d_in[8];
  (void)in_sizes; (void)n_in; (void)out_size; (void)ws_size;

  char* ws = (char*)d_ws;
  size_t off = 0;
  auto alloc = [&](size_t bytes) {
    void* p = ws + off;
    off += (bytes + 255) & ~(size_t)255;
    return p;
  };
  ushort* Xb  = (ushort*)alloc((size_t)T_ * HID_ * 2);
  ushort* Wqt = (ushort*)alloc((size_t)HID_ * HID_ * 2);
  ushort* Wkt = (ushort*)alloc((size_t)256 * HID_ * 2);  // contiguous with Wvt
  ushort* Wvt = (ushort*)alloc((size_t)256 * HID_ * 2);
  ushort* Wot = (ushort*)alloc((size_t)HID_ * HID_ * 2);
  ushort* qb  = (ushort*)alloc((size_t)T_ * 1536 * 2);
  ushort* kvb = (ushort*)alloc((size_t)T_ * 512 * 2);
  ushort* ka  = (ushort*)alloc((size_t)T_ * 256 * 2);
  ushort* vt  = (ushort*)alloc((size_t)T_ * 256 * 2);
  ushort* qa = Xb;  // q attn layout overwrites Xb after last GEMM
  ushort* ao = qb;  // attn out overwrites q-proj after normrope-q consumed it

  const float SCL = 0.08838834764831845f * 1.44269504088896f;  // D^-0.5 * log2(e)

  cvt_f32_bf16<<<(T_ * HID_ / 4 + 255) / 256, 256, 0, stream>>>(hs, Xb, T_ * HID_);
  transpose_cvt<<<dim3(HID_ / 32, HID_ / 32), 256, 0, stream>>>(Wq, Wqt, HID_, HID_);
  transpose_cvt<<<dim3(HID_ / 32, 256 / 32), 256, 0, stream>>>(Wk, Wkt, HID_, 256);
  transpose_cvt<<<dim3(HID_ / 32, 256 / 32), 256, 0, stream>>>(Wv, Wvt, HID_, 256);
  transpose_cvt<<<dim3(HID_ / 32, HID_ / 32), 256, 0, stream>>>(Wo, Wot, HID_, HID_);

  gemm_bt<0><<<dim3(T_ / 128, 1536 / 128), 256, 0, stream>>>(Xb, Wqt, qb, T_, 1536, HID_);
  gemm_bt<0><<<dim3(T_ / 128, 512 / 128), 256, 0, stream>>>(Xb, Wkt, kvb, T_, 512, HID_);

  normrope<H_><<<(T_ * H_ + 3) / 4, 256, 0, stream>>>(qb, 1536, qw, cosb, sinb, qa, SCL);
  normrope<KV_><<<(T_ * KV_ + 3) / 4, 256, 0, stream>>>(kvb, 512, kw, cosb, sinb, ka, 1.0f);
  vtrans<<<dim3(S_ / 32, 128 / 32, B_ * KV_), 256, 0, stream>>>(kvb, 512, 256, vt);

  attn<<<768, 256, 0, stream>>>(qa, ka, vt, ao);

  gemm_bt<1><<<dim3(T_ / 128, 1536 / 128), 256, 0, stream>>>(ao, Wot, (float*)d_out, T_, 1536, HID_);
}

// Round 8
// 236.243 us; speedup vs baseline: 2.4279x; 1.2345x over previous
//
#include <hip/hip_runtime.h>
#include <hip/hip_bf16.h>
#include <stdint.h>

#define H_   12
#define KV_  2
#define D_   128
#define HID_ 1536
#define B_   4
#define S_   2048
#define T_   (B_*S_)

typedef __attribute__((ext_vector_type(8))) short  bf16x8;
typedef __attribute__((ext_vector_type(4))) float  f32x4;

__device__ __forceinline__ ushort f2bf(float f) {
  union { float f; uint32_t u; } v; v.f = f;
  uint32_t u = v.u;
  return (ushort)((u + 0x7fffu + ((u >> 16) & 1u)) >> 16);  // RNE
}
__device__ __forceinline__ float bf2f(ushort u) {
  union { uint32_t u; float f; } v; v.u = ((uint32_t)u) << 16;
  return v.f;
}
__device__ __forceinline__ uint32_t cvtpk_bf16(float lo, float hi) {
  uint32_t r;
  asm("v_cvt_pk_bf16_f32 %0, %1, %2" : "=v"(r) : "v"(lo), "v"(hi));
  return r;
}

__device__ __forceinline__ void gload_lds16(const void* g, void* l) {
  __builtin_amdgcn_global_load_lds(
      (const __attribute__((address_space(1))) uint32_t*)g,
      (__attribute__((address_space(3))) uint32_t*)l, 16, 0, 0);
}

// ---------------- elementwise fp32 -> bf16 ----------------
__global__ __launch_bounds__(256) void cvt_f32_bf16(const float* __restrict__ in,
                                                    ushort* __restrict__ out, int n) {
  int i = (blockIdx.x * 256 + threadIdx.x) * 4;
  if (i + 3 < n) {
    float4 v = *(const float4*)&in[i];
    ushort4 o;
    o.x = f2bf(v.x); o.y = f2bf(v.y); o.z = f2bf(v.z); o.w = f2bf(v.w);
    *(ushort4*)&out[i] = o;
  }
}

// ---------------- transpose + convert: W (K,N) fp32 -> Wt (N,K) bf16 ----------------
__global__ __launch_bounds__(256) void transpose_cvt(const float* __restrict__ W,
                                                     ushort* __restrict__ Wt,
                                                     int K, int N) {
  __shared__ float tile[32][33];
  int k0 = blockIdx.x * 32, n0 = blockIdx.y * 32;
  int tx = threadIdx.x & 31, ty = threadIdx.x >> 5;  // ty 0..7
#pragma unroll
  for (int i = 0; i < 32; i += 8)
    tile[ty + i][tx] = W[(long)(k0 + ty + i) * N + n0 + tx];
  __syncthreads();
#pragma unroll
  for (int i = 0; i < 32; i += 8)
    Wt[(long)(n0 + ty + i) * K + k0 + tx] = f2bf(tile[tx][ty + i]);
}

// ---------------- GEMM: C(M,N) = A(M,K;lda) * Bt(N,K)^T, bf16 in, bf16/f32 out ----------------
template <int OUT_F32>
__global__ __launch_bounds__(256, 2) void gemm_bt(const ushort* __restrict__ A,
                                                  const ushort* __restrict__ Bt,
                                                  void* __restrict__ Cv,
                                                  int M, int N, int K, int lda) {
  __shared__ ushort lA[128 * 32];
  __shared__ ushort lB[128 * 32];
  const int tid = threadIdx.x;
  const int lane = tid & 63, w = tid >> 6;
  const int wr = w >> 1, wc = w & 1;
  const int l15 = lane & 15, lh = lane >> 4;
  const long m0 = (long)blockIdx.x * 128, n0 = (long)blockIdx.y * 128;
  const ushort* Ab = A + m0 * lda;
  const ushort* Bb = Bt + n0 * K;
  const int sr = tid >> 2;
  const int sc = (tid & 3) * 8;
  const int ldsoff = w * 512;
  f32x4 acc[4][4] = {};

  for (int k0 = 0; k0 < K; k0 += 32) {
#pragma unroll
    for (int it = 0; it < 2; ++it) {
      gload_lds16(Ab + (long)(it * 64 + sr) * lda + k0 + sc, &lA[it * 2048 + ldsoff]);
      gload_lds16(Bb + (long)(it * 64 + sr) * K + k0 + sc, &lB[it * 2048 + ldsoff]);
    }
    __syncthreads();
    bf16x8 af[4], bfr[4];
    const int ra = (wr * 64 + l15) * 32 + lh * 8;
    const int rb = (wc * 64 + l15) * 32 + lh * 8;
#pragma unroll
    for (int i = 0; i < 4; ++i) {
      af[i]  = *(const bf16x8*)&lA[ra + i * 16 * 32];
      bfr[i] = *(const bf16x8*)&lB[rb + i * 16 * 32];
    }
#pragma unroll
    for (int i = 0; i < 4; ++i)
#pragma unroll
      for (int j = 0; j < 4; ++j)
        acc[i][j] = __builtin_amdgcn_mfma_f32_16x16x32_bf16(af[i], bfr[j], acc[i][j], 0, 0, 0);
    __syncthreads();
  }
#pragma unroll
  for (int i = 0; i < 4; ++i) {
#pragma unroll
    for (int q = 0; q < 4; ++q) {
      long row = m0 + wr * 64 + i * 16 + lh * 4 + q;
#pragma unroll
      for (int j = 0; j < 4; ++j) {
        long col = n0 + wc * 64 + j * 16 + l15;
        float v = acc[i][j][q];
        if (OUT_F32) ((float*)Cv)[row * N + col] = v;
        else         ((ushort*)Cv)[row * N + col] = f2bf(v);
      }
    }
  }
}

// ---------------- fused RMSNorm + RoPE, wave per (token, head) [used for K only] ----------------
template <int NH>
__global__ __launch_bounds__(256) void normrope(const ushort* __restrict__ X,  // [T][xstride] (pre-offset)
                                                int xstride,
                                                const float* __restrict__ w,   // [128]
                                                const float* __restrict__ cosb,// [T][64]
                                                const float* __restrict__ sinb,
                                                ushort* __restrict__ Y,        // [B][NH][S][128]
                                                float scale) {
  int wid = (int)((blockIdx.x * 256 + threadIdx.x) >> 6);
  int lane = threadIdx.x & 63;
  if (wid >= T_ * NH) return;
  int t = wid / NH, h = wid % NH;
  const ushort* xr = X + (long)t * xstride + h * 128;
  float x1 = bf2f(xr[lane]);
  float x2 = bf2f(xr[lane + 64]);
  float ss = x1 * x1 + x2 * x2;
#pragma unroll
  for (int off = 32; off; off >>= 1) ss += __shfl_xor(ss, off);
  float r = rsqrtf(ss * (1.0f / 128.0f) + 1e-6f);
  float y1 = x1 * r * w[lane] * scale;
  float y2 = x2 * r * w[lane + 64] * scale;
  float c = cosb[(long)t * 64 + lane], s = sinb[(long)t * 64 + lane];
  float o1 = y1 * c - y2 * s;
  float o2 = y1 * s + y2 * c;
  int b = t / S_, sq = t % S_;
  ushort* yr = Y + ((long)(b * NH + h) * S_ + sq) * 128;
  yr[lane]      = f2bf(o1);
  yr[lane + 64] = f2bf(o2);
}

// ---------------- V transpose: [T][vstride] (col voff+) -> [B][KV][128][S] ----------------
__global__ __launch_bounds__(256) void vtrans(const ushort* __restrict__ V, int vstride, int voff,
                                              ushort* __restrict__ Vt) {
  __shared__ ushort tile[32][33];
  int s0 = blockIdx.x * 32, d0 = blockIdx.y * 32;
  int bk = blockIdx.z;
  int b = bk / KV_, g = bk % KV_;
  int tx = threadIdx.x & 31, ty = threadIdx.x >> 5;
#pragma unroll
  for (int i = 0; i < 32; i += 8)
    tile[ty + i][tx] = V[(long)(b * S_ + s0 + ty + i) * vstride + voff + g * 128 + d0 + tx];
  __syncthreads();
#pragma unroll
  for (int i = 0; i < 32; i += 8)
    Vt[(long)(bk * 128 + d0 + ty + i) * S_ + s0 + tx] = tile[tx][ty + i];
}

// ---------------- flash attention, causal, GQA, fused Q-normrope ----------------
// r7 no-spill structure + pure descending LPT (heavy first, lightest LAST -> tiny drain tail).
// Q is read from the fused QKV projection output and RMSNorm+RoPE'd IN REGISTERS
// (RoPE partner of qf[m][kd] is qf[m][kd^2] -> all in-lane; rowsum = 2 shfl_xor).
// O is written back into the same qkv cells (single reader+writer per region).
// T5 setprio around MFMA clusters.
__global__ __launch_bounds__(256, 2) void attn(ushort* __restrict__ QKV,      // [T][2048]; cols h*128 Q in / O out
                                               const ushort* __restrict__ Ka, // [B][KV][S][D]
                                               const ushort* __restrict__ Vt, // [B][KV][D][S]
                                               const float* __restrict__ qnw, // [128]
                                               const float* __restrict__ cosb,// [T][64]
                                               const float* __restrict__ sinb) {
  __shared__ ushort lK[64 * 128];   // [k][d], xor-swizzled (full 16-slot bijection)
  __shared__ ushort lV[128 * 64];   // [d][k], xor-swizzled
  __shared__ ushort lP[4 * 32 * 32];// per-wave [q][32k half], xor-swizzled
  const int tid = threadIdx.x, lane = tid & 63, w = tid >> 6;
  const int l15 = lane & 15, lh = lane >> 4;
  char* cK = (char*)lK;
  char* cV = (char*)lV;
  char* cP = (char*)lP + w * 2048;
  const int swzK = l15 << 4;
  const int swzV = (l15 & 7) << 4;
  const int swzP = (l15 & 3) << 4;
  const float SCL = 0.08838834764831845f * 1.44269504088896f;  // D^-0.5 * log2(e)

  // pure descending LPT: heavy q-tiles first, lightest last
  const int qt = 15 - (int)(blockIdx.x / 48);
  const int bh = blockIdx.x % 48;
  const int b = bh / H_, h = bh % H_, g = h / (H_ / KV_);
  const int q0 = qt * 128;
  const ushort* Kb = Ka + (long)(b * KV_ + g) * S_ * 128;
  const ushort* Vb = Vt + (long)(b * KV_ + g) * 128 * S_;

  // ---- Q load + in-register RMSNorm + RoPE (+ SCL prescale) ----
  bf16x8 qf[2][4];
#pragma unroll
  for (int m = 0; m < 2; ++m) {
    const long tt = (long)b * S_ + q0 + w * 32 + m * 16 + l15;
    const ushort* xr = QKV + tt * 2048 + h * 128;
    bf16x8 raw[4];
#pragma unroll
    for (int kd = 0; kd < 4; ++kd)
      raw[kd] = *(const bf16x8*)&xr[kd * 32 + lh * 8];
    float ss = 0.f;
#pragma unroll
    for (int kd = 0; kd < 4; ++kd)
#pragma unroll
      for (int e = 0; e < 8; ++e) {
        float v = bf2f((ushort)raw[kd][e]);
        ss += v * v;
      }
    ss += __shfl_xor(ss, 16);
    ss += __shfl_xor(ss, 32);
    const float rn = rsqrtf(ss * (1.0f / 128.0f) + 1e-6f) * SCL;
    const float* cR = cosb + tt * 64;
    const float* sR = sinb + tt * 64;
#pragma unroll
    for (int kp = 0; kp < 2; ++kp) {   // pair (kp, kp+2): cols ci and ci+64
      bf16x8 qlo, qhi;
#pragma unroll
      for (int e = 0; e < 8; ++e) {
        const int ci = kp * 32 + lh * 8 + e;
        float c = cR[ci], s = sR[ci];
        float y1 = bf2f((ushort)raw[kp][e])     * rn * qnw[ci];
        float y2 = bf2f((ushort)raw[kp + 2][e]) * rn * qnw[64 + ci];
        qlo[e] = (short)f2bf(y1 * c - y2 * s);
        qhi[e] = (short)f2bf(y1 * s + y2 * c);
      }
      qf[m][kp]     = qlo;
      qf[m][kp + 2] = qhi;
    }
  }

  f32x4 o[2][8] = {};
  float mr[2] = {-INFINITY, -INFINITY};
  float lr[2] = {0.f, 0.f};
  const int nt = 2 * qt + 2;

  bf16x8 kreg[4], vreg[4];
#define LDTILE(K0) do { \
  _Pragma("unroll") for (int it = 0; it < 4; ++it) \
    kreg[it] = *(const bf16x8*)&Kb[(long)((K0) + it * 16 + (tid >> 4)) * 128 + (tid & 15) * 8]; \
  _Pragma("unroll") for (int it = 0; it < 4; ++it) \
    vreg[it] = *(const bf16x8*)&Vb[(long)(it * 32 + (tid >> 3)) * S_ + (K0) + (tid & 7) * 8]; \
} while (0)

  LDTILE(0);
  for (int t = 0; t < nt; ++t) {
    const int k0 = t * 64;
    __syncthreads();   // previous tile's consumers done
#pragma unroll
    for (int it = 0; it < 4; ++it) {
      int r = it * 16 + (tid >> 4);   // r&15 == tid>>4
      *(bf16x8*)(cK + r * 256 + (((tid & 15) * 16) ^ (((tid >> 4) & 15) << 4))) = kreg[it];
    }
#pragma unroll
    for (int it = 0; it < 4; ++it) {
      int r = it * 32 + (tid >> 3);
      *(bf16x8*)(cV + r * 128 + (((tid & 7) * 16) ^ ((r & 7) << 4))) = vreg[it];
    }
    __syncthreads();   // stage visible
    if (t + 1 < nt) LDTILE(k0 + 64);   // in flight during compute

    if (k0 <= q0 + w * 32 + 31) {
      // ---- QK^T, swapped operands: sfr[m][n] = S[k-row][q-col=l15] ----
      f32x4 sfr[2][4] = {};
      __builtin_amdgcn_s_setprio(1);
#pragma unroll
      for (int kd = 0; kd < 4; ++kd) {
        bf16x8 kf[4];
#pragma unroll
        for (int n = 0; n < 4; ++n)
          kf[n] = *(const bf16x8*)(cK + (n * 16 + l15) * 256 + ((kd * 64 + lh * 16) ^ swzK));
#pragma unroll
        for (int m = 0; m < 2; ++m)
#pragma unroll
          for (int n = 0; n < 4; ++n)
            sfr[m][n] = __builtin_amdgcn_mfma_f32_16x16x32_bf16(kf[n], qf[m][kd], sfr[m][n], 0, 0, 0);
      }
      __builtin_amdgcn_s_setprio(0);
      const bool boundary = (k0 + 63 > q0 + w * 32);
      float pm[2];
#pragma unroll
      for (int m = 0; m < 2; ++m) {
        const int rowm = q0 + w * 32 + m * 16 + l15;
        if (boundary) {
#pragma unroll
          for (int n = 0; n < 4; ++n) {
            int kb = k0 + n * 16 + lh * 4;
#pragma unroll
            for (int qr = 0; qr < 4; ++qr)
              if (kb + qr > rowm) sfr[m][n][qr] = -INFINITY;
          }
        }
        float x = fmaxf(fmaxf(sfr[m][0][0], sfr[m][0][1]), fmaxf(sfr[m][0][2], sfr[m][0][3]));
#pragma unroll
        for (int n = 1; n < 4; ++n)
          x = fmaxf(x, fmaxf(fmaxf(sfr[m][n][0], sfr[m][n][1]), fmaxf(sfr[m][n][2], sfr[m][n][3])));
        x = fmaxf(x, __shfl_xor(x, 16));
        x = fmaxf(x, __shfl_xor(x, 32));
        pm[m] = x;
      }
      // T13 defer-max
      int ok = (pm[0] <= mr[0] + 8.f) && (pm[1] <= mr[1] + 8.f);
      if (!__all(ok)) {
        float corr[2];
#pragma unroll
        for (int m = 0; m < 2; ++m) {
          float mn = fmaxf(mr[m], pm[m]);
          corr[m] = exp2f(mr[m] - mn);
          mr[m] = mn;
          lr[m] *= corr[m];
        }
#pragma unroll
        for (int m = 0; m < 2; ++m) {
          float cf[4];
#pragma unroll
          for (int qr = 0; qr < 4; ++qr) cf[qr] = __shfl(corr[m], lh * 4 + qr);
#pragma unroll
          for (int d = 0; d < 8; ++d)
#pragma unroll
            for (int qr = 0; qr < 4; ++qr) o[m][d][qr] *= cf[qr];
        }
      }
      // ---- P = exp2(S - m) in regs, row-sum ----
#pragma unroll
      for (int m = 0; m < 2; ++m) {
        float rs = 0.f;
#pragma unroll
        for (int n = 0; n < 4; ++n) {
          float p0 = exp2f(sfr[m][n][0] - mr[m]);
          float p1 = exp2f(sfr[m][n][1] - mr[m]);
          float p2 = exp2f(sfr[m][n][2] - mr[m]);
          float p3 = exp2f(sfr[m][n][3] - mr[m]);
          sfr[m][n][0] = p0; sfr[m][n][1] = p1; sfr[m][n][2] = p2; sfr[m][n][3] = p3;
          rs += (p0 + p1) + (p2 + p3);
        }
        rs += __shfl_xor(rs, 16);
        rs += __shfl_xor(rs, 32);
        lr[m] += rs;
      }
      // ---- PV per 32-wide half: pack P half -> per-wave lP, read pf, MFMA ----
#pragma unroll
      for (int kf2 = 0; kf2 < 2; ++kf2) {
#pragma unroll
        for (int m = 0; m < 2; ++m)
#pragma unroll
          for (int nl = 0; nl < 2; ++nl) {
            const int n = kf2 * 2 + nl;
            uint2 pk;
            pk.x = cvtpk_bf16(sfr[m][n][0], sfr[m][n][1]);
            pk.y = cvtpk_bf16(sfr[m][n][2], sfr[m][n][3]);
            *(uint2*)(cP + (m * 16 + l15) * 64 + ((nl * 32 + lh * 8) ^ swzP)) = pk;
          }
        const int cb = (lh * 16) ^ swzP;
        bf16x8 pf0 = *(const bf16x8*)(cP + l15 * 64 + cb);
        bf16x8 pf1 = *(const bf16x8*)(cP + (16 + l15) * 64 + cb);
        const int cv = (kf2 * 64 + lh * 16);
        __builtin_amdgcn_s_setprio(1);
#pragma unroll
        for (int dblk = 0; dblk < 8; ++dblk) {
          bf16x8 vf = *(const bf16x8*)(cV + (dblk * 16 + l15) * 128 + (cv ^ swzV));
          o[0][dblk] = __builtin_amdgcn_mfma_f32_16x16x32_bf16(pf0, vf, o[0][dblk], 0, 0, 0);
          o[1][dblk] = __builtin_amdgcn_mfma_f32_16x16x32_bf16(pf1, vf, o[1][dblk], 0, 0, 0);
        }
        __builtin_amdgcn_s_setprio(0);
      }
    }
  }
#undef LDTILE
  // ---- epilogue: write O back into qkv (same cells Q came from) ----
#pragma unroll
  for (int m = 0; m < 2; ++m) {
    float inv = 1.f / lr[m];
#pragma unroll
    for (int qr = 0; qr < 4; ++qr) {
      float iv = __shfl(inv, lh * 4 + qr);
      long trow = (long)b * S_ + q0 + w * 32 + m * 16 + lh * 4 + qr;
#pragma unroll
      for (int dblk = 0; dblk < 8; ++dblk)
        QKV[trow * 2048 + h * 128 + dblk * 16 + l15] = f2bf(o[m][dblk][qr] * iv);
    }
  }
}

extern "C" void kernel_launch(void* const* d_in, const int* in_sizes, int n_in,
                              void* d_out, int out_size, void* d_ws, size_t ws_size,
                              hipStream_t stream) {
  const float* hs   = (const float*)d_in[0];
  const float* cosb = (const float*)d_in[1];
  const float* sinb = (const float*)d_in[2];
  const float* Wq   = (const float*)d_in[3];
  const float* Wk   = (const float*)d_in[4];
  const float* Wv   = (const float*)d_in[5];
  const float* Wo   = (const float*)d_in[6];
  const float* qw   = (const float*)d_in[7];
  const float* kw   = (const float*)d_in[8];
  (void)in_sizes; (void)n_in; (void)out_size; (void)ws_size;

  char* ws = (char*)d_ws;
  size_t off = 0;
  auto alloc = [&](size_t bytes) {
    void* p = ws + off;
    off += (bytes + 255) & ~(size_t)255;
    return p;
  };
  ushort* Xb  = (ushort*)alloc((size_t)T_ * HID_ * 2);
  ushort* Wqt = (ushort*)alloc((size_t)HID_ * HID_ * 2);  // rows 0-1535   (Wq^T)
  ushort* Wkt = (ushort*)alloc((size_t)256 * HID_ * 2);   // rows 1536-1791 (Wk^T) -- contiguous
  ushort* Wvt = (ushort*)alloc((size_t)256 * HID_ * 2);   // rows 1792-2047 (Wv^T) -- contiguous
  ushort* Wot = (ushort*)alloc((size_t)HID_ * HID_ * 2);
  ushort* qkv = (ushort*)alloc((size_t)T_ * 2048 * 2);    // fused QKV proj out; Q cols become attn O
  ushort* ka  = (ushort*)alloc((size_t)T_ * 256 * 2);
  ushort* vt  = (ushort*)alloc((size_t)T_ * 256 * 2);

  cvt_f32_bf16<<<(T_ * HID_ / 4 + 255) / 256, 256, 0, stream>>>(hs, Xb, T_ * HID_);
  transpose_cvt<<<dim3(HID_ / 32, HID_ / 32), 256, 0, stream>>>(Wq, Wqt, HID_, HID_);
  transpose_cvt<<<dim3(HID_ / 32, 256 / 32), 256, 0, stream>>>(Wk, Wkt, HID_, 256);
  transpose_cvt<<<dim3(HID_ / 32, 256 / 32), 256, 0, stream>>>(Wv, Wvt, HID_, 256);
  transpose_cvt<<<dim3(HID_ / 32, HID_ / 32), 256, 0, stream>>>(Wo, Wot, HID_, HID_);

  // fused Q|K|V projection: C[T][2048] = Xb * [Wqt;Wkt;Wvt]^T
  gemm_bt<0><<<dim3(T_ / 128, 2048 / 128), 256, 0, stream>>>(Xb, Wqt, qkv, T_, 2048, HID_, HID_);

  normrope<KV_><<<(T_ * KV_ + 3) / 4, 256, 0, stream>>>(qkv + 1536, 2048, kw, cosb, sinb, ka, 1.0f);
  vtrans<<<dim3(S_ / 32, 128 / 32, B_ * KV_), 256, 0, stream>>>(qkv, 2048, 1792, vt);

  attn<<<768, 256, 0, stream>>>(qkv, ka, vt, qw, cosb, sinb);

  // O-proj: A = qkv cols 0-1535 (attn output), lda=2048
  gemm_bt<1><<<dim3(T_ / 128, 1536 / 128), 256, 0, stream>>>(qkv, Wot, (float*)d_out, T_, 1536, HID_, 2048);
}

// Round 9
// 232.707 us; speedup vs baseline: 2.4648x; 1.0152x over previous
//
#include <hip/hip_runtime.h>
#include <hip/hip_bf16.h>
#include <stdint.h>

#define H_   12
#define KV_  2
#define D_   128
#define HID_ 1536
#define B_   4
#define S_   2048
#define T_   (B_*S_)

typedef __attribute__((ext_vector_type(8))) short  bf16x8;
typedef __attribute__((ext_vector_type(4))) float  f32x4;

__device__ __forceinline__ ushort f2bf(float f) {
  union { float f; uint32_t u; } v; v.f = f;
  uint32_t u = v.u;
  return (ushort)((u + 0x7fffu + ((u >> 16) & 1u)) >> 16);  // RNE
}
__device__ __forceinline__ float bf2f(ushort u) {
  union { uint32_t u; float f; } v; v.u = ((uint32_t)u) << 16;
  return v.f;
}
__device__ __forceinline__ uint32_t cvtpk_bf16(float lo, float hi) {
  uint32_t r;
  asm("v_cvt_pk_bf16_f32 %0, %1, %2" : "=v"(r) : "v"(lo), "v"(hi));
  return r;
}

__device__ __forceinline__ void gload_lds16(const void* g, void* l) {
  __builtin_amdgcn_global_load_lds(
      (const __attribute__((address_space(1))) uint32_t*)g,
      (__attribute__((address_space(3))) uint32_t*)l, 16, 0, 0);
}

// ---------------- elementwise fp32 -> bf16 ----------------
__global__ __launch_bounds__(256) void cvt_f32_bf16(const float* __restrict__ in,
                                                    ushort* __restrict__ out, int n) {
  int i = (blockIdx.x * 256 + threadIdx.x) * 4;
  if (i + 3 < n) {
    float4 v = *(const float4*)&in[i];
    ushort4 o;
    o.x = f2bf(v.x); o.y = f2bf(v.y); o.z = f2bf(v.z); o.w = f2bf(v.w);
    *(ushort4*)&out[i] = o;
  }
}

// ---------------- transpose + convert: W (K,N) fp32 -> Wt (N,K) bf16 ----------------
__global__ __launch_bounds__(256) void transpose_cvt(const float* __restrict__ W,
                                                     ushort* __restrict__ Wt,
                                                     int K, int N) {
  __shared__ float tile[32][33];
  int k0 = blockIdx.x * 32, n0 = blockIdx.y * 32;
  int tx = threadIdx.x & 31, ty = threadIdx.x >> 5;  // ty 0..7
#pragma unroll
  for (int i = 0; i < 32; i += 8)
    tile[ty + i][tx] = W[(long)(k0 + ty + i) * N + n0 + tx];
  __syncthreads();
#pragma unroll
  for (int i = 0; i < 32; i += 8)
    Wt[(long)(n0 + ty + i) * K + k0 + tx] = f2bf(tile[tx][ty + i]);
}

// ---------------- GEMM: C(M,N) = A(M,K;lda) * Bt(N,K)^T, bf16 in, bf16/f32 out ----------------
template <int OUT_F32>
__global__ __launch_bounds__(256, 2) void gemm_bt(const ushort* __restrict__ A,
                                                  const ushort* __restrict__ Bt,
                                                  void* __restrict__ Cv,
                                                  int M, int N, int K, int lda) {
  __shared__ ushort lA[128 * 32];
  __shared__ ushort lB[128 * 32];
  const int tid = threadIdx.x;
  const int lane = tid & 63, w = tid >> 6;
  const int wr = w >> 1, wc = w & 1;
  const int l15 = lane & 15, lh = lane >> 4;
  const long m0 = (long)blockIdx.x * 128, n0 = (long)blockIdx.y * 128;
  const ushort* Ab = A + m0 * lda;
  const ushort* Bb = Bt + n0 * K;
  const int sr = tid >> 2;
  const int sc = (tid & 3) * 8;
  const int ldsoff = w * 512;
  f32x4 acc[4][4] = {};

  for (int k0 = 0; k0 < K; k0 += 32) {
#pragma unroll
    for (int it = 0; it < 2; ++it) {
      gload_lds16(Ab + (long)(it * 64 + sr) * lda + k0 + sc, &lA[it * 2048 + ldsoff]);
      gload_lds16(Bb + (long)(it * 64 + sr) * K + k0 + sc, &lB[it * 2048 + ldsoff]);
    }
    __syncthreads();
    bf16x8 af[4], bfr[4];
    const int ra = (wr * 64 + l15) * 32 + lh * 8;
    const int rb = (wc * 64 + l15) * 32 + lh * 8;
#pragma unroll
    for (int i = 0; i < 4; ++i) {
      af[i]  = *(const bf16x8*)&lA[ra + i * 16 * 32];
      bfr[i] = *(const bf16x8*)&lB[rb + i * 16 * 32];
    }
#pragma unroll
    for (int i = 0; i < 4; ++i)
#pragma unroll
      for (int j = 0; j < 4; ++j)
        acc[i][j] = __builtin_amdgcn_mfma_f32_16x16x32_bf16(af[i], bfr[j], acc[i][j], 0, 0, 0);
    __syncthreads();
  }
#pragma unroll
  for (int i = 0; i < 4; ++i) {
#pragma unroll
    for (int q = 0; q < 4; ++q) {
      long row = m0 + wr * 64 + i * 16 + lh * 4 + q;
#pragma unroll
      for (int j = 0; j < 4; ++j) {
        long col = n0 + wc * 64 + j * 16 + l15;
        float v = acc[i][j][q];
        if (OUT_F32) ((float*)Cv)[row * N + col] = v;
        else         ((ushort*)Cv)[row * N + col] = f2bf(v);
      }
    }
  }
}

// ---------------- fused RMSNorm + RoPE, wave per (token, head) [used for K only] ----------------
template <int NH>
__global__ __launch_bounds__(256) void normrope(const ushort* __restrict__ X,  // [T][xstride] (pre-offset)
                                                int xstride,
                                                const float* __restrict__ w,   // [128]
                                                const float* __restrict__ cosb,// [T][64]
                                                const float* __restrict__ sinb,
                                                ushort* __restrict__ Y,        // [B][NH][S][128]
                                                float scale) {
  int wid = (int)((blockIdx.x * 256 + threadIdx.x) >> 6);
  int lane = threadIdx.x & 63;
  if (wid >= T_ * NH) return;
  int t = wid / NH, h = wid % NH;
  const ushort* xr = X + (long)t * xstride + h * 128;
  float x1 = bf2f(xr[lane]);
  float x2 = bf2f(xr[lane + 64]);
  float ss = x1 * x1 + x2 * x2;
#pragma unroll
  for (int off = 32; off; off >>= 1) ss += __shfl_xor(ss, off);
  float r = rsqrtf(ss * (1.0f / 128.0f) + 1e-6f);
  float y1 = x1 * r * w[lane] * scale;
  float y2 = x2 * r * w[lane + 64] * scale;
  float c = cosb[(long)t * 64 + lane], s = sinb[(long)t * 64 + lane];
  float o1 = y1 * c - y2 * s;
  float o2 = y1 * s + y2 * c;
  int b = t / S_, sq = t % S_;
  ushort* yr = Y + ((long)(b * NH + h) * S_ + sq) * 128;
  yr[lane]      = f2bf(o1);
  yr[lane + 64] = f2bf(o2);
}

// ---------------- V transpose: [T][vstride] (col voff+) -> [B][KV][128][S] ----------------
__global__ __launch_bounds__(256) void vtrans(const ushort* __restrict__ V, int vstride, int voff,
                                              ushort* __restrict__ Vt) {
  __shared__ ushort tile[32][33];
  int s0 = blockIdx.x * 32, d0 = blockIdx.y * 32;
  int bk = blockIdx.z;
  int b = bk / KV_, g = bk % KV_;
  int tx = threadIdx.x & 31, ty = threadIdx.x >> 5;
#pragma unroll
  for (int i = 0; i < 32; i += 8)
    tile[ty + i][tx] = V[(long)(b * S_ + s0 + ty + i) * vstride + voff + g * 128 + d0 + tx];
  __syncthreads();
#pragma unroll
  for (int i = 0; i < 32; i += 8)
    Vt[(long)(bk * 128 + d0 + ty + i) * S_ + s0 + tx] = tile[tx][ty + i];
}

// ---------------- flash attention, causal, GQA, fused Q-normrope, FIXED-MAX softmax ----------------
// Qwen3 QK-norm bound: |q.k| <= ||q||*||k|| = 128 (RMSNorm rows, unit norm weights), so
// |S * D^-0.5 * log2e| <= 128*0.1276 = 16.33 (+bf16 rounding slack < 0.3). Fixed shift M0=17
// makes P = exp2(Slog2 - 17) in (0,1.4]: softmax identical (shift cancels), NO online max,
// NO rescale, NO per-tile reductions -- row-sum is deferred to ONE epilogue shuffle-reduce.
__global__ __launch_bounds__(256, 2) void attn(ushort* __restrict__ QKV,      // [T][2048]; cols h*128 Q in / O out
                                               const ushort* __restrict__ Ka, // [B][KV][S][D]
                                               const ushort* __restrict__ Vt, // [B][KV][D][S]
                                               const float* __restrict__ qnw, // [128]
                                               const float* __restrict__ cosb,// [T][64]
                                               const float* __restrict__ sinb) {
  __shared__ ushort lK[64 * 128];   // [k][d], xor-swizzled (full 16-slot bijection)
  __shared__ ushort lV[128 * 64];   // [d][k], xor-swizzled
  __shared__ ushort lP[4 * 32 * 32];// per-wave [q][32k half], xor-swizzled
  const int tid = threadIdx.x, lane = tid & 63, w = tid >> 6;
  const int l15 = lane & 15, lh = lane >> 4;
  char* cK = (char*)lK;
  char* cV = (char*)lV;
  char* cP = (char*)lP + w * 2048;
  const int swzK = l15 << 4;
  const int swzV = (l15 & 7) << 4;
  const int swzP = (l15 & 3) << 4;
  const float SCL = 0.08838834764831845f * 1.44269504088896f;  // D^-0.5 * log2(e)
  const float M0  = 17.0f;                                     // fixed softmax shift

  // pure descending LPT: heavy q-tiles first, lightest last
  const int qt = 15 - (int)(blockIdx.x / 48);
  const int bh = blockIdx.x % 48;
  const int b = bh / H_, h = bh % H_, g = h / (H_ / KV_);
  const int q0 = qt * 128;
  const ushort* Kb = Ka + (long)(b * KV_ + g) * S_ * 128;
  const ushort* Vb = Vt + (long)(b * KV_ + g) * 128 * S_;

  // ---- Q load + in-register RMSNorm + RoPE (+ SCL prescale) ----
  bf16x8 qf[2][4];
#pragma unroll
  for (int m = 0; m < 2; ++m) {
    const long tt = (long)b * S_ + q0 + w * 32 + m * 16 + l15;
    const ushort* xr = QKV + tt * 2048 + h * 128;
    bf16x8 raw[4];
#pragma unroll
    for (int kd = 0; kd < 4; ++kd)
      raw[kd] = *(const bf16x8*)&xr[kd * 32 + lh * 8];
    float ss = 0.f;
#pragma unroll
    for (int kd = 0; kd < 4; ++kd)
#pragma unroll
      for (int e = 0; e < 8; ++e) {
        float v = bf2f((ushort)raw[kd][e]);
        ss += v * v;
      }
    ss += __shfl_xor(ss, 16);
    ss += __shfl_xor(ss, 32);
    const float rn = rsqrtf(ss * (1.0f / 128.0f) + 1e-6f) * SCL;
    const float* cR = cosb + tt * 64;
    const float* sR = sinb + tt * 64;
#pragma unroll
    for (int kp = 0; kp < 2; ++kp) {   // pair (kp, kp+2): cols ci and ci+64
      bf16x8 qlo, qhi;
#pragma unroll
      for (int e = 0; e < 8; ++e) {
        const int ci = kp * 32 + lh * 8 + e;
        float c = cR[ci], s = sR[ci];
        float y1 = bf2f((ushort)raw[kp][e])     * rn * qnw[ci];
        float y2 = bf2f((ushort)raw[kp + 2][e]) * rn * qnw[64 + ci];
        qlo[e] = (short)f2bf(y1 * c - y2 * s);
        qhi[e] = (short)f2bf(y1 * s + y2 * c);
      }
      qf[m][kp]     = qlo;
      qf[m][kp + 2] = qhi;
    }
  }

  f32x4 o[2][8] = {};
  float lr[2] = {0.f, 0.f};   // per-lane PARTIAL row-sums; reduced once in epilogue
  const int nt = 2 * qt + 2;

  bf16x8 kreg[4], vreg[4];
#define LDTILE(K0) do { \
  _Pragma("unroll") for (int it = 0; it < 4; ++it) \
    kreg[it] = *(const bf16x8*)&Kb[(long)((K0) + it * 16 + (tid >> 4)) * 128 + (tid & 15) * 8]; \
  _Pragma("unroll") for (int it = 0; it < 4; ++it) \
    vreg[it] = *(const bf16x8*)&Vb[(long)(it * 32 + (tid >> 3)) * S_ + (K0) + (tid & 7) * 8]; \
} while (0)

  LDTILE(0);
  for (int t = 0; t < nt; ++t) {
    const int k0 = t * 64;
    __syncthreads();   // previous tile's consumers done
#pragma unroll
    for (int it = 0; it < 4; ++it) {
      int r = it * 16 + (tid >> 4);   // r&15 == tid>>4
      *(bf16x8*)(cK + r * 256 + (((tid & 15) * 16) ^ (((tid >> 4) & 15) << 4))) = kreg[it];
    }
#pragma unroll
    for (int it = 0; it < 4; ++it) {
      int r = it * 32 + (tid >> 3);
      *(bf16x8*)(cV + r * 128 + (((tid & 7) * 16) ^ ((r & 7) << 4))) = vreg[it];
    }
    __syncthreads();   // stage visible
    if (t + 1 < nt) LDTILE(k0 + 64);   // in flight during compute

    if (k0 <= q0 + w * 32 + 31) {
      // ---- QK^T, swapped operands: sfr[m][n] = S[k-row][q-col=l15] ----
      f32x4 sfr[2][4] = {};
      __builtin_amdgcn_s_setprio(1);
#pragma unroll
      for (int kd = 0; kd < 4; ++kd) {
        bf16x8 kf[4];
#pragma unroll
        for (int n = 0; n < 4; ++n)
          kf[n] = *(const bf16x8*)(cK + (n * 16 + l15) * 256 + ((kd * 64 + lh * 16) ^ swzK));
#pragma unroll
        for (int m = 0; m < 2; ++m)
#pragma unroll
          for (int n = 0; n < 4; ++n)
            sfr[m][n] = __builtin_amdgcn_mfma_f32_16x16x32_bf16(kf[n], qf[m][kd], sfr[m][n], 0, 0, 0);
      }
      __builtin_amdgcn_s_setprio(0);
      const bool boundary = (k0 + 63 > q0 + w * 32);
      if (boundary) {
#pragma unroll
        for (int m = 0; m < 2; ++m) {
          const int rowm = q0 + w * 32 + m * 16 + l15;
#pragma unroll
          for (int n = 0; n < 4; ++n) {
            int kb = k0 + n * 16 + lh * 4;
#pragma unroll
            for (int qr = 0; qr < 4; ++qr)
              if (kb + qr > rowm) sfr[m][n][qr] = -INFINITY;
          }
        }
      }
      // ---- P = exp2(S - M0) in regs; accumulate per-lane partial row-sum ----
#pragma unroll
      for (int m = 0; m < 2; ++m) {
#pragma unroll
        for (int n = 0; n < 4; ++n) {
          float p0 = exp2f(sfr[m][n][0] - M0);
          float p1 = exp2f(sfr[m][n][1] - M0);
          float p2 = exp2f(sfr[m][n][2] - M0);
          float p3 = exp2f(sfr[m][n][3] - M0);
          sfr[m][n][0] = p0; sfr[m][n][1] = p1; sfr[m][n][2] = p2; sfr[m][n][3] = p3;
          lr[m] += (p0 + p1) + (p2 + p3);
        }
      }
      // ---- PV per 32-wide half: pack P half -> per-wave lP, read pf, MFMA ----
#pragma unroll
      for (int kf2 = 0; kf2 < 2; ++kf2) {
#pragma unroll
        for (int m = 0; m < 2; ++m)
#pragma unroll
          for (int nl = 0; nl < 2; ++nl) {
            const int n = kf2 * 2 + nl;
            uint2 pk;
            pk.x = cvtpk_bf16(sfr[m][n][0], sfr[m][n][1]);
            pk.y = cvtpk_bf16(sfr[m][n][2], sfr[m][n][3]);
            *(uint2*)(cP + (m * 16 + l15) * 64 + ((nl * 32 + lh * 8) ^ swzP)) = pk;
          }
        const int cb = (lh * 16) ^ swzP;
        bf16x8 pf0 = *(const bf16x8*)(cP + l15 * 64 + cb);
        bf16x8 pf1 = *(const bf16x8*)(cP + (16 + l15) * 64 + cb);
        const int cv = (kf2 * 64 + lh * 16);
        __builtin_amdgcn_s_setprio(1);
#pragma unroll
        for (int dblk = 0; dblk < 8; ++dblk) {
          bf16x8 vf = *(const bf16x8*)(cV + (dblk * 16 + l15) * 128 + (cv ^ swzV));
          o[0][dblk] = __builtin_amdgcn_mfma_f32_16x16x32_bf16(pf0, vf, o[0][dblk], 0, 0, 0);
          o[1][dblk] = __builtin_amdgcn_mfma_f32_16x16x32_bf16(pf1, vf, o[1][dblk], 0, 0, 0);
        }
        __builtin_amdgcn_s_setprio(0);
      }
    }
  }
#undef LDTILE
  // ---- epilogue: ONE deferred row-sum reduction, then write O back into qkv ----
#pragma unroll
  for (int m = 0; m < 2; ++m) {
    lr[m] += __shfl_xor(lr[m], 16);
    lr[m] += __shfl_xor(lr[m], 32);
    float inv = 1.f / lr[m];
#pragma unroll
    for (int qr = 0; qr < 4; ++qr) {
      float iv = __shfl(inv, lh * 4 + qr);
      long trow = (long)b * S_ + q0 + w * 32 + m * 16 + lh * 4 + qr;
#pragma unroll
      for (int dblk = 0; dblk < 8; ++dblk)
        QKV[trow * 2048 + h * 128 + dblk * 16 + l15] = f2bf(o[m][dblk][qr] * iv);
    }
  }
}

extern "C" void kernel_launch(void* const* d_in, const int* in_sizes, int n_in,
                              void* d_out, int out_size, void* d_ws, size_t ws_size,
                              hipStream_t stream) {
  const float* hs   = (const float*)d_in[0];
  const float* cosb = (const float*)d_in[1];
  const float* sinb = (const float*)d_in[2];
  const float* Wq   = (const float*)d_in[3];
  const float* Wk   = (const float*)d_in[4];
  const float* Wv   = (const float*)d_in[5];
  const float* Wo   = (const float*)d_in[6];
  const float* qw   = (const float*)d_in[7];
  const float* kw   = (const float*)d_in[8];
  (void)in_sizes; (void)n_in; (void)out_size; (void)ws_size;

  char* ws = (char*)d_ws;
  size_t off = 0;
  auto alloc = [&](size_t bytes) {
    void* p = ws + off;
    off += (bytes + 255) & ~(size_t)255;
    return p;
  };
  ushort* Xb  = (ushort*)alloc((size_t)T_ * HID_ * 2);
  ushort* Wqt = (ushort*)alloc((size_t)HID_ * HID_ * 2);  // rows 0-1535   (Wq^T)
  ushort* Wkt = (ushort*)alloc((size_t)256 * HID_ * 2);   // rows 1536-1791 (Wk^T) -- contiguous
  ushort* Wvt = (ushort*)alloc((size_t)256 * HID_ * 2);   // rows 1792-2047 (Wv^T) -- contiguous
  ushort* Wot = (ushort*)alloc((size_t)HID_ * HID_ * 2);
  ushort* qkv = (ushort*)alloc((size_t)T_ * 2048 * 2);    // fused QKV proj out; Q cols become attn O
  ushort* ka  = (ushort*)alloc((size_t)T_ * 256 * 2);
  ushort* vt  = (ushort*)alloc((size_t)T_ * 256 * 2);

  cvt_f32_bf16<<<(T_ * HID_ / 4 + 255) / 256, 256, 0, stream>>>(hs, Xb, T_ * HID_);
  transpose_cvt<<<dim3(HID_ / 32, HID_ / 32), 256, 0, stream>>>(Wq, Wqt, HID_, HID_);
  transpose_cvt<<<dim3(HID_ / 32, 256 / 32), 256, 0, stream>>>(Wk, Wkt, HID_, 256);
  transpose_cvt<<<dim3(HID_ / 32, 256 / 32), 256, 0, stream>>>(Wv, Wvt, HID_, 256);
  transpose_cvt<<<dim3(HID_ / 32, HID_ / 32), 256, 0, stream>>>(Wo, Wot, HID_, HID_);

  // fused Q|K|V projection: C[T][2048] = Xb * [Wqt;Wkt;Wvt]^T
  gemm_bt<0><<<dim3(T_ / 128, 2048 / 128), 256, 0, stream>>>(Xb, Wqt, qkv, T_, 2048, HID_, HID_);

  normrope<KV_><<<(T_ * KV_ + 3) / 4, 256, 0, stream>>>(qkv + 1536, 2048, kw, cosb, sinb, ka, 1.0f);
  vtrans<<<dim3(S_ / 32, 128 / 32, B_ * KV_), 256, 0, stream>>>(qkv, 2048, 1792, vt);

  attn<<<768, 256, 0, stream>>>(qkv, ka, vt, qw, cosb, sinb);

  // O-proj: A = qkv cols 0-1535 (attn output), lda=2048
  gemm_bt<1><<<dim3(T_ / 128, 1536 / 128), 256, 0, stream>>>(qkv, Wot, (float*)d_out, T_, 1536, HID_, 2048);
}